// Round 1
// baseline (647.838 us; speedup 1.0000x reference)
//
#include <hip/hip_runtime.h>
#include <stdint.h>
#include <stddef.h>

#define NTOK 8192
#define DDIM 1024
#define HDIM 2048
#define NEXP 8

typedef __attribute__((ext_vector_type(8))) short short8;
typedef __attribute__((ext_vector_type(4))) float floatx4;
typedef __attribute__((ext_vector_type(4))) unsigned short ushortx4;

#define AS1 __attribute__((address_space(1)))
#define AS3 __attribute__((address_space(3)))

// ws layout (bytes)
constexpr size_t OFF_CNT  = 0;                                      // 8 ints
constexpr size_t OFF_LIST = 256;                                    // E*N ints
constexpr size_t OFF_WTS  = OFF_LIST + (size_t)NEXP * NTOK * 4;     // E*N floats
constexpr size_t OFF_XBF  = OFF_WTS + (size_t)NEXP * NTOK * 4;      // N*D bf16
constexpr size_t OFF_W1T  = OFF_XBF + (size_t)NTOK * DDIM * 2;      // E*H*D bf16 (K-contig)
constexpr size_t OFF_W2T  = OFF_W1T + (size_t)NEXP * DDIM * HDIM * 2; // E*D*H bf16 (K-contig)
constexpr size_t OFF_H    = OFF_W2T + (size_t)NEXP * DDIM * HDIM * 2; // (K*N)*H bf16
// total = OFF_H + 2*NTOK*HDIM*2  ~= 145 MB

__device__ __forceinline__ unsigned short f2bf(float f) {
  union { float f; unsigned u; } v; v.f = f;
  unsigned r = v.u + 0x7FFFu + ((v.u >> 16) & 1u);   // RNE, finite inputs
  return (unsigned short)(r >> 16);
}

// ---------------- gating: one wave per token ----------------
__global__ __launch_bounds__(256) void gate_kernel(
    const float* __restrict__ x, const float* __restrict__ Wg,
    const float* __restrict__ bg, const float* __restrict__ noise,
    int* __restrict__ counts, int* __restrict__ lists, float* __restrict__ wts) {
  int lane = threadIdx.x & 63;
  int wid  = threadIdx.x >> 6;
  int token = blockIdx.x * 4 + wid;
  const float* xr = x + (size_t)token * DDIM;
  double acc[NEXP];
#pragma unroll
  for (int e = 0; e < NEXP; ++e) acc[e] = 0.0;
  for (int d = lane; d < DDIM; d += 64) {
    float xv = xr[d];
    const floatx4* wp = (const floatx4*)(Wg + d * NEXP);
    floatx4 w0 = wp[0], w1 = wp[1];
#pragma unroll
    for (int j = 0; j < 4; ++j) {
      acc[j]     += (double)xv * (double)w0[j];
      acc[4 + j] += (double)xv * (double)w1[j];
    }
  }
#pragma unroll
  for (int e = 0; e < NEXP; ++e)
#pragma unroll
    for (int off = 32; off > 0; off >>= 1) acc[e] += __shfl_xor(acc[e], off);
  if (lane == 0) {
    float nv[NEXP];
#pragma unroll
    for (int e = 0; e < NEXP; ++e) {
      float lg = (float)(acc[e] + (double)bg[e]);
      nv[e] = lg + 0.1f * noise[token * NEXP + e];
    }
    int i1 = 0; float v1 = nv[0];
#pragma unroll
    for (int e = 1; e < NEXP; ++e) if (nv[e] > v1) { v1 = nv[e]; i1 = e; }
    int i2 = -1; float v2 = -3.4e38f;
#pragma unroll
    for (int e = 0; e < NEXP; ++e) if (e != i1 && nv[e] > v2) { v2 = nv[e]; i2 = e; }
    float tt  = expf(v2 - v1);            // softmax over [v1, v2], v1 = max
    float w1s = 1.0f / (1.0f + tt);
    float w2s = tt / (1.0f + tt);
    int s1 = atomicAdd(&counts[i1], 1);
    lists[i1 * NTOK + s1] = token; wts[i1 * NTOK + s1] = w1s;
    int s2 = atomicAdd(&counts[i2], 1);
    lists[i2 * NTOK + s2] = token; wts[i2 * NTOK + s2] = w2s;
  }
}

// ---------------- x -> bf16 pack ----------------
__global__ __launch_bounds__(256) void pack_x_kernel(const float* __restrict__ x,
                                                     unsigned short* __restrict__ xbf) {
  size_t i = (size_t)blockIdx.x * 256 + threadIdx.x;  // 4 floats per thread
  floatx4 v = ((const floatx4*)x)[i];
  ushortx4 o;
#pragma unroll
  for (int j = 0; j < 4; ++j) o[j] = f2bf(v[j]);
  *(ushortx4*)(xbf + i * 4) = o;
}

// ---------------- W [e][R][C] f32 -> WT [e][C][R] bf16 ----------------
__global__ __launch_bounds__(256) void transpose_cvt_kernel(
    const float* __restrict__ W, unsigned short* __restrict__ WT, int R, int C) {
  __shared__ float tile[64][65];
  int e = blockIdx.z;
  const float* Win = W + (size_t)e * R * C;
  unsigned short* Wout = WT + (size_t)e * R * C;
  int c0 = blockIdx.x * 64, r0 = blockIdx.y * 64;
  int tx = threadIdx.x & 63, ty = threadIdx.x >> 6;
#pragma unroll
  for (int i = ty; i < 64; i += 4)
    tile[i][tx] = Win[(size_t)(r0 + i) * C + c0 + tx];
  __syncthreads();
#pragma unroll
  for (int i = ty; i < 64; i += 4)
    Wout[(size_t)(c0 + i) * R + r0 + tx] = f2bf(tile[tx][i]);
}

// ---------------- grouped GEMM, 128x128 tile, BK=32, 4 waves ----------------
// A: [rows][KDIM] bf16 (G1: gathered token rows of xbf; G2: h rows)
// B: [e][NDIM][KDIM] bf16 (K-contig)
// LDS tile rows are 64B; chunk-rotation swizzle: 16B chunk c stored at (c + row/2)&3.
template <int KDIM, int NDIM, bool IS_G1>
__global__ __launch_bounds__(256) void moe_gemm_kernel(
    const unsigned short* __restrict__ Abase,
    const unsigned short* __restrict__ Bbase,
    const float* __restrict__ bias,
    const int* __restrict__ counts, const int* __restrict__ lists,
    const float* __restrict__ wts,
    unsigned short* __restrict__ Hout, float* __restrict__ Out) {
  __shared__ unsigned short lds[16384];  // As: 2x4096 ushort, Bs: 2x4096 ushort
  int e = blockIdx.z;
  int cnt[NEXP];
#pragma unroll
  for (int i = 0; i < NEXP; ++i) cnt[i] = counts[i];
  int Me = cnt[e];
  int bx = blockIdx.x;  // row tile
  if (bx * 128 >= Me) return;
  int by = blockIdx.y;  // col tile
  int off_e = 0;
#pragma unroll
  for (int i = 0; i < NEXP; ++i) if (i < e) off_e += cnt[i];

  int t = threadIdx.x;
  int lane = t & 63, wid = t >> 6;

  // staging sources: instr i covers LDS bytes i*4096 + wid*1024 + lane*16
  const unsigned short* srcA[2];
  const unsigned short* srcB[2];
#pragma unroll
  for (int i = 0; i < 2; ++i) {
    int row = i * 64 + wid * 16 + (lane >> 2);   // tile row 0..127
    int sc  = lane & 3;                          // stored chunk
    int c   = (sc - (row >> 1)) & 3;             // logical 16B chunk (8 bf16)
    int lr  = bx * 128 + row;
    if (IS_G1) {
      int tok = (lr < Me) ? lists[e * NTOK + lr] : 0;
      srcA[i] = Abase + (size_t)tok * KDIM + c * 8;
    } else {
      int grow = (lr < Me) ? (off_e + lr) : off_e;
      srcA[i] = Abase + (size_t)grow * KDIM + c * 8;
    }
    int col = by * 128 + row;
    srcB[i] = Bbase + ((size_t)e * NDIM + col) * KDIM + c * 8;
  }

  // fragment read offsets (ushorts), constant across K-steps
  int r = lane & 15, g = lane >> 4;
  int wr = wid >> 1, wc = wid & 1;
  int aoff[4], boff[4];
#pragma unroll
  for (int m = 0; m < 4; ++m) {
    int rowa = wr * 64 + m * 16 + r;
    aoff[m] = rowa * 32 + ((g + (rowa >> 1)) & 3) * 8;
    int rowb = wc * 64 + m * 16 + r;
    boff[m] = rowb * 32 + ((g + (rowb >> 1)) & 3) * 8;
  }

  floatx4 acc[4][4];
#pragma unroll
  for (int m = 0; m < 4; ++m)
#pragma unroll
    for (int n = 0; n < 4; ++n) acc[m][n] = (floatx4){0.f, 0.f, 0.f, 0.f};

  auto stage = [&](int buf, int k0) {
    unsigned short* ab = lds + buf * 4096;
    unsigned short* bb = lds + 8192 + buf * 4096;
#pragma unroll
    for (int i = 0; i < 2; ++i) {
      __builtin_amdgcn_global_load_lds((const AS1 void*)(srcA[i] + k0),
                                       (AS3 void*)(ab + i * 2048 + wid * 512), 16, 0, 0);
      __builtin_amdgcn_global_load_lds((const AS1 void*)(srcB[i] + k0),
                                       (AS3 void*)(bb + i * 2048 + wid * 512), 16, 0, 0);
    }
  };

  stage(0, 0);
  __syncthreads();
  constexpr int NT = KDIM / 32;
  for (int kt = 0; kt < NT; ++kt) {
    if (kt + 1 < NT) stage((kt + 1) & 1, (kt + 1) * 32);
    const unsigned short* ab = lds + (kt & 1) * 4096;
    const unsigned short* bb = lds + 8192 + (kt & 1) * 4096;
    short8 a[4], b[4];
#pragma unroll
    for (int m = 0; m < 4; ++m) a[m] = *(const short8*)(ab + aoff[m]);
#pragma unroll
    for (int n = 0; n < 4; ++n) b[n] = *(const short8*)(bb + boff[n]);
#pragma unroll
    for (int m = 0; m < 4; ++m)
#pragma unroll
      for (int n = 0; n < 4; ++n)
        acc[m][n] = __builtin_amdgcn_mfma_f32_16x16x32_bf16(a[m], b[n], acc[m][n], 0, 0, 0);
    __syncthreads();
  }

  // epilogue: C/D layout col=lane&15, row=(lane>>4)*4+reg  [m89-verified]
  if constexpr (IS_G1) {
#pragma unroll
    for (int m = 0; m < 4; ++m) {
#pragma unroll
      for (int i = 0; i < 4; ++i) {
        int lrow = bx * 128 + wr * 64 + m * 16 + g * 4 + i;
        if (lrow < Me) {
          size_t hrow = (size_t)(off_e + lrow) * HDIM;
#pragma unroll
          for (int n = 0; n < 4; ++n) {
            int col = by * 128 + wc * 64 + n * 16 + r;
            float v = acc[m][n][i] + bias[e * NDIM + col];
            Hout[hrow + col] = f2bf(fmaxf(v, 0.f));
          }
        }
      }
    }
  } else {
#pragma unroll
    for (int m = 0; m < 4; ++m) {
#pragma unroll
      for (int i = 0; i < 4; ++i) {
        int lrow = bx * 128 + wr * 64 + m * 16 + g * 4 + i;
        if (lrow < Me) {
          int tok  = lists[e * NTOK + lrow];
          float w  = wts[e * NTOK + lrow];
          float* orow = Out + (size_t)tok * DDIM;
#pragma unroll
          for (int n = 0; n < 4; ++n) {
            int col = by * 128 + wc * 64 + n * 16 + r;
            float v = acc[m][n][i] + bias[e * NDIM + col];
            atomicAdd(orow + col, w * v);  // exactly 2 adds per element -> commutative, deterministic
          }
        }
      }
    }
  }
}

extern "C" void kernel_launch(void* const* d_in, const int* in_sizes, int n_in,
                              void* d_out, int out_size, void* d_ws, size_t ws_size,
                              hipStream_t stream) {
  (void)in_sizes; (void)n_in; (void)ws_size;
  const float* x     = (const float*)d_in[0];
  const float* W1    = (const float*)d_in[1];
  const float* b1    = (const float*)d_in[2];
  const float* W2    = (const float*)d_in[3];
  const float* b2    = (const float*)d_in[4];
  const float* Wg    = (const float*)d_in[5];
  const float* bg    = (const float*)d_in[6];
  const float* noise = (const float*)d_in[7];
  float* out = (float*)d_out;

  char* ws = (char*)d_ws;
  int*            counts = (int*)(ws + OFF_CNT);
  int*            lists  = (int*)(ws + OFF_LIST);
  float*          wts    = (float*)(ws + OFF_WTS);
  unsigned short* xbf    = (unsigned short*)(ws + OFF_XBF);
  unsigned short* w1t    = (unsigned short*)(ws + OFF_W1T);
  unsigned short* w2t    = (unsigned short*)(ws + OFF_W2T);
  unsigned short* h      = (unsigned short*)(ws + OFF_H);

  hipMemsetAsync(d_out, 0, (size_t)out_size * sizeof(float), stream);
  hipMemsetAsync(counts, 0, 256, stream);

  gate_kernel<<<NTOK / 4, 256, 0, stream>>>(x, Wg, bg, noise, counts, lists, wts);
  pack_x_kernel<<<(NTOK * DDIM) / 1024, 256, 0, stream>>>(x, xbf);
  transpose_cvt_kernel<<<dim3(HDIM / 64, DDIM / 64, NEXP), 256, 0, stream>>>(W1, w1t, DDIM, HDIM);
  transpose_cvt_kernel<<<dim3(DDIM / 64, HDIM / 64, NEXP), 256, 0, stream>>>(W2, w2t, HDIM, DDIM);

  moe_gemm_kernel<DDIM, HDIM, true>
      <<<dim3(64, HDIM / 128, NEXP), 256, 0, stream>>>(xbf, w1t, b1, counts, lists, wts, h, nullptr);
  moe_gemm_kernel<HDIM, DDIM, false>
      <<<dim3(64, DDIM / 128, NEXP), 256, 0, stream>>>(h, w2t, b2, counts, lists, wts, nullptr, out);
}

// Round 2
// 586.688 us; speedup vs baseline: 1.1042x; 1.1042x over previous
//
#include <hip/hip_runtime.h>
#include <stdint.h>
#include <stddef.h>

#define NTOK 8192
#define DDIM 1024
#define HDIM 2048
#define NEXP 8

typedef __attribute__((ext_vector_type(8))) short short8;
typedef __attribute__((ext_vector_type(8))) unsigned short ushort8;
typedef __attribute__((ext_vector_type(4))) float floatx4;
typedef __attribute__((ext_vector_type(4))) unsigned short ushortx4;

#define AS1 __attribute__((address_space(1)))
#define AS3 __attribute__((address_space(3)))

// ws layout (bytes)
constexpr size_t OFF_CNT  = 0;                                        // 8 ints
constexpr size_t OFF_LIST = 256;                                      // E*N ints
constexpr size_t OFF_WTS  = OFF_LIST + (size_t)NEXP * NTOK * 4;       // E*N floats
constexpr size_t OFF_XBF  = OFF_WTS + (size_t)NEXP * NTOK * 4;        // N*D bf16
constexpr size_t OFF_W1T  = OFF_XBF + (size_t)NTOK * DDIM * 2;        // E*H*D bf16 (K-contig)
constexpr size_t OFF_W2T  = OFF_W1T + (size_t)NEXP * DDIM * HDIM * 2; // E*D*H bf16 (K-contig)
constexpr size_t OFF_H    = OFF_W2T + (size_t)NEXP * DDIM * HDIM * 2; // (K*N)*H bf16

__device__ __forceinline__ unsigned short f2bf(float f) {
  union { float f; unsigned u; } v; v.f = f;
  unsigned r = v.u + 0x7FFFu + ((v.u >> 16) & 1u);   // RNE, finite inputs
  return (unsigned short)(r >> 16);
}

// ---------------- gating: one wave per token ----------------
__global__ __launch_bounds__(256) void gate_kernel(
    const float* __restrict__ x, const float* __restrict__ Wg,
    const float* __restrict__ bg, const float* __restrict__ noise,
    int* __restrict__ counts, int* __restrict__ lists, float* __restrict__ wts) {
  int lane = threadIdx.x & 63;
  int wid  = threadIdx.x >> 6;
  int token = blockIdx.x * 4 + wid;
  const float* xr = x + (size_t)token * DDIM;
  double acc[NEXP];
#pragma unroll
  for (int e = 0; e < NEXP; ++e) acc[e] = 0.0;
  for (int d = lane; d < DDIM; d += 64) {
    float xv = xr[d];
    const floatx4* wp = (const floatx4*)(Wg + d * NEXP);
    floatx4 w0 = wp[0], w1 = wp[1];
#pragma unroll
    for (int j = 0; j < 4; ++j) {
      acc[j]     += (double)xv * (double)w0[j];
      acc[4 + j] += (double)xv * (double)w1[j];
    }
  }
#pragma unroll
  for (int e = 0; e < NEXP; ++e)
#pragma unroll
    for (int off = 32; off > 0; off >>= 1) acc[e] += __shfl_xor(acc[e], off);
  if (lane == 0) {
    float nv[NEXP];
#pragma unroll
    for (int e = 0; e < NEXP; ++e) {
      float lg = (float)(acc[e] + (double)bg[e]);
      nv[e] = lg + 0.1f * noise[token * NEXP + e];
    }
    int i1 = 0; float v1 = nv[0];
#pragma unroll
    for (int e = 1; e < NEXP; ++e) if (nv[e] > v1) { v1 = nv[e]; i1 = e; }
    int i2 = -1; float v2 = -3.4e38f;
#pragma unroll
    for (int e = 0; e < NEXP; ++e) if (e != i1 && nv[e] > v2) { v2 = nv[e]; i2 = e; }
    float tt  = expf(v2 - v1);
    float w1s = 1.0f / (1.0f + tt);
    float w2s = tt / (1.0f + tt);
    int s1 = atomicAdd(&counts[i1], 1);
    lists[i1 * NTOK + s1] = token; wts[i1 * NTOK + s1] = w1s;
    int s2 = atomicAdd(&counts[i2], 1);
    lists[i2 * NTOK + s2] = token; wts[i2 * NTOK + s2] = w2s;
  }
}

// ---------------- x -> bf16 pack ----------------
__global__ __launch_bounds__(256) void pack_x_kernel(const float* __restrict__ x,
                                                     unsigned short* __restrict__ xbf) {
  size_t i = (size_t)blockIdx.x * 256 + threadIdx.x;
  floatx4 v = ((const floatx4*)x)[i];
  ushortx4 o;
#pragma unroll
  for (int j = 0; j < 4; ++j) o[j] = f2bf(v[j]);
  *(ushortx4*)(xbf + i * 4) = o;
}

// ---------------- W [e][R][C] f32 -> WT [e][C][R] bf16, vectorized stores ----------------
__global__ __launch_bounds__(256) void transpose_cvt_kernel(
    const float* __restrict__ W, unsigned short* __restrict__ WT, int R, int C) {
  __shared__ float tile[64][65];
  int e = blockIdx.z;
  const float* Win = W + (size_t)e * R * C;
  unsigned short* Wout = WT + (size_t)e * R * C;
  int c0 = blockIdx.x * 64, r0 = blockIdx.y * 64;
  int tx = threadIdx.x & 63, ty = threadIdx.x >> 6;
#pragma unroll
  for (int i = ty; i < 64; i += 4)
    tile[i][tx] = Win[(size_t)(r0 + i) * C + c0 + tx];
  __syncthreads();
  int cc = threadIdx.x >> 2, seg = (threadIdx.x & 3) * 16;
  ushort8 o0, o1;
#pragma unroll
  for (int j = 0; j < 8; ++j) o0[j] = f2bf(tile[seg + j][cc]);
#pragma unroll
  for (int j = 0; j < 8; ++j) o1[j] = f2bf(tile[seg + 8 + j][cc]);
  unsigned short* outp = Wout + (size_t)(c0 + cc) * R + r0 + seg;
  *(ushort8*)(outp) = o0;
  *(ushort8*)(outp + 8) = o1;
}

// ---------------- grouped GEMM, 256x256 tile, BK=64, 8 waves, 8-phase counted-vmcnt ----------------
// LDS (dynamic, 128KB): A: [buf][256 rows][64 k] @ 0 + buf*32768 ; B: same @ 65536 + buf*32768
// chunk swizzle within a 128B row: stored_chunk = chunk ^ (row & 7)  (applied on global SOURCE + read addr)
#define STAGE_HT(q, sp0, sp1, th) do {                                              \
    size_t ko_ = (size_t)(th) * 64;                                                 \
    char* d_ = smem + ((q) & 1) * 65536 + ((th) & 1) * 32768 + ((q) >> 1) * 16384   \
               + (size_t)tid * 16;                                                  \
    __builtin_amdgcn_global_load_lds((const AS1 void*)((sp0) + ko_), (AS3 void*)d_, 16, 0, 0);          \
    __builtin_amdgcn_global_load_lds((const AS1 void*)((sp1) + ko_), (AS3 void*)(d_ + 8192), 16, 0, 0); \
  } while (0)

template <int KDIM, int NDIM, bool IS_G1>
__global__ __launch_bounds__(512, 2) void moe_gemm_kernel(
    const unsigned short* __restrict__ Abase,
    const unsigned short* __restrict__ Bbase,
    const float* __restrict__ bias,
    const int* __restrict__ counts, const int* __restrict__ lists,
    const float* __restrict__ wts,
    unsigned short* __restrict__ Hout, float* __restrict__ Out) {
  extern __shared__ char smem[];
  constexpr int NT  = KDIM / 64;
  constexpr int NBY = NDIM / 256;
  static_assert(KDIM % 64 == 0 && NDIM % 256 == 0, "shape");

  // XCD-chunked bijective block swizzle (nwg % 8 == 0)
  int nwg = gridDim.x;
  int q8  = nwg >> 3;
  int bid = blockIdx.x;
  int orig = (bid & 7) * q8 + (bid >> 3);
  int bx  = orig & 31;
  int tmp = orig >> 5;
  int by  = tmp % NBY;
  int e   = tmp / NBY;

  int Me, off_e = 0;
  {
    int c[8];
#pragma unroll
    for (int i = 0; i < 8; ++i) c[i] = counts[i];
    Me = c[e];
#pragma unroll
    for (int i = 0; i < 8; ++i) if (i < e) off_e += c[i];
  }
  if (bx * 256 >= Me) return;

  int tid = threadIdx.x;
  int lane = tid & 63, wid = tid >> 6;
  int wr = wid >> 2, wc = wid & 3;
  int r16 = lane & 15, g4 = lane >> 4;

  // staging sources (pre-swizzled chunk within each 128B row-segment)
  auto mksrc = [&](int q, int j) -> const unsigned short* {
    int rowl = (q >> 1) * 128 + j * 64 + (tid >> 3);
    int c = (tid & 7) ^ ((tid >> 3) & 7);
    if (q & 1) {
      int gcol = by * 256 + rowl;
      return Bbase + ((size_t)e * NDIM + gcol) * (size_t)KDIM + c * 8;
    } else {
      int lr = bx * 256 + rowl;
      if (IS_G1) {
        int tok = lists[e * NTOK + (lr < Me ? lr : 0)];
        return Abase + (size_t)tok * KDIM + c * 8;
      } else {
        int grow = off_e + (lr < Me ? lr : 0);
        return Abase + (size_t)grow * KDIM + c * 8;
      }
    }
  };
  const unsigned short* sp00 = mksrc(0, 0); const unsigned short* sp01 = mksrc(0, 1);
  const unsigned short* sp10 = mksrc(1, 0); const unsigned short* sp11 = mksrc(1, 1);
  const unsigned short* sp20 = mksrc(2, 0); const unsigned short* sp21 = mksrc(2, 1);
  const unsigned short* sp30 = mksrc(3, 0); const unsigned short* sp31 = mksrc(3, 1);

  // fragment read addressing (swizzled)
  int csw0 = ((g4)     ^ (lane & 7)) * 16;
  int csw1 = ((4 + g4) ^ (lane & 7)) * 16;
  int arow = (wr * 128 + r16) * 128;
  int brow = (wc * 64  + r16) * 128;

  floatx4 acc[8][4];
#pragma unroll
  for (int m = 0; m < 8; ++m)
#pragma unroll
    for (int n = 0; n < 4; ++n) acc[m][n] = (floatx4){0.f, 0.f, 0.f, 0.f};

  short8 afq[4][2], bfA[2][2], bfB[2][2];

  // prologue: HT stream A0(0),B0(0),A1(0),B1(0),A0(1)
  STAGE_HT(0, sp00, sp01, 0);
  STAGE_HT(1, sp10, sp11, 0);
  STAGE_HT(2, sp20, sp21, 0);
  STAGE_HT(3, sp30, sp31, 0);
  STAGE_HT(0, sp00, sp01, 1);
  asm volatile("s_waitcnt vmcnt(2)" ::: "memory");
  __builtin_amdgcn_s_barrier();

  for (int t = 0; t < NT; ++t) {
    const char* pa = smem + (t & 1) * 32768;
    const char* pb = smem + 65536 + (t & 1) * 32768;
    // ---- P0: read A[m0-3], B[n0-1]; stage B0(t+1); MFMA (m0-3 x n0-1)
#pragma unroll
    for (int m = 0; m < 4; ++m) {
      afq[m][0] = *(const short8*)(pa + arow + m * 2048 + csw0);
      afq[m][1] = *(const short8*)(pa + arow + m * 2048 + csw1);
    }
#pragma unroll
    for (int n = 0; n < 2; ++n) {
      bfA[n][0] = *(const short8*)(pb + brow + n * 2048 + csw0);
      bfA[n][1] = *(const short8*)(pb + brow + n * 2048 + csw1);
    }
    if (t + 1 < NT) STAGE_HT(1, sp10, sp11, t + 1);
    __builtin_amdgcn_s_barrier();
    asm volatile("s_waitcnt lgkmcnt(0)" ::: "memory");
    __builtin_amdgcn_sched_barrier(0);
    __builtin_amdgcn_s_setprio(1);
#pragma unroll
    for (int m = 0; m < 4; ++m)
#pragma unroll
      for (int n = 0; n < 2; ++n) {
        acc[m][n] = __builtin_amdgcn_mfma_f32_16x16x32_bf16(afq[m][0], bfA[n][0], acc[m][n], 0, 0, 0);
        acc[m][n] = __builtin_amdgcn_mfma_f32_16x16x32_bf16(afq[m][1], bfA[n][1], acc[m][n], 0, 0, 0);
      }
    __builtin_amdgcn_s_setprio(0);
    __builtin_amdgcn_s_barrier();
    // ---- P1: read B[n2-3]; stage A1(t+1); MFMA (m0-3 x n2-3)
#pragma unroll
    for (int n = 0; n < 2; ++n) {
      bfB[n][0] = *(const short8*)(pb + brow + (n + 2) * 2048 + csw0);
      bfB[n][1] = *(const short8*)(pb + brow + (n + 2) * 2048 + csw1);
    }
    if (t + 1 < NT) STAGE_HT(2, sp20, sp21, t + 1);
    __builtin_amdgcn_s_barrier();
    asm volatile("s_waitcnt lgkmcnt(0)" ::: "memory");
    __builtin_amdgcn_sched_barrier(0);
    __builtin_amdgcn_s_setprio(1);
#pragma unroll
    for (int m = 0; m < 4; ++m)
#pragma unroll
      for (int n = 0; n < 2; ++n) {
        acc[m][n + 2] = __builtin_amdgcn_mfma_f32_16x16x32_bf16(afq[m][0], bfB[n][0], acc[m][n + 2], 0, 0, 0);
        acc[m][n + 2] = __builtin_amdgcn_mfma_f32_16x16x32_bf16(afq[m][1], bfB[n][1], acc[m][n + 2], 0, 0, 0);
      }
    __builtin_amdgcn_s_setprio(0);
    __builtin_amdgcn_s_barrier();
    // ---- P2: read A[m4-7] (reuse afq); stage B1(t+1); MFMA (m4-7 x n0-1)
#pragma unroll
    for (int m = 0; m < 4; ++m) {
      afq[m][0] = *(const short8*)(pa + arow + (m + 4) * 2048 + csw0);
      afq[m][1] = *(const short8*)(pa + arow + (m + 4) * 2048 + csw1);
    }
    if (t + 1 < NT) STAGE_HT(3, sp30, sp31, t + 1);
    __builtin_amdgcn_s_barrier();
    asm volatile("s_waitcnt lgkmcnt(0)" ::: "memory");
    __builtin_amdgcn_sched_barrier(0);
    __builtin_amdgcn_s_setprio(1);
#pragma unroll
    for (int m = 0; m < 4; ++m)
#pragma unroll
      for (int n = 0; n < 2; ++n) {
        acc[m + 4][n] = __builtin_amdgcn_mfma_f32_16x16x32_bf16(afq[m][0], bfA[n][0], acc[m + 4][n], 0, 0, 0);
        acc[m + 4][n] = __builtin_amdgcn_mfma_f32_16x16x32_bf16(afq[m][1], bfA[n][1], acc[m + 4][n], 0, 0, 0);
      }
    __builtin_amdgcn_s_setprio(0);
    __builtin_amdgcn_s_barrier();
    // ---- P3: stage A0(t+2); MFMA (m4-7 x n2-3); counted vmcnt; barrier
    if (t + 2 < NT) STAGE_HT(0, sp00, sp01, t + 2);
    __builtin_amdgcn_s_barrier();
    __builtin_amdgcn_s_setprio(1);
#pragma unroll
    for (int m = 0; m < 4; ++m)
#pragma unroll
      for (int n = 0; n < 2; ++n) {
        acc[m + 4][n + 2] = __builtin_amdgcn_mfma_f32_16x16x32_bf16(afq[m][0], bfB[n][0], acc[m + 4][n + 2], 0, 0, 0);
        acc[m + 4][n + 2] = __builtin_amdgcn_mfma_f32_16x16x32_bf16(afq[m][1], bfB[n][1], acc[m + 4][n + 2], 0, 0, 0);
      }
    __builtin_amdgcn_s_setprio(0);
    if (t + 2 < NT) { asm volatile("s_waitcnt vmcnt(2)" ::: "memory"); }
    else            { asm volatile("s_waitcnt vmcnt(0)" ::: "memory"); }
    __builtin_amdgcn_s_barrier();
  }

  // epilogue: C/D layout col=lane&15, row=(lane>>4)*4+reg
  if constexpr (IS_G1) {
#pragma unroll
    for (int m = 0; m < 8; ++m) {
#pragma unroll
      for (int i = 0; i < 4; ++i) {
        int lrow = bx * 256 + wr * 128 + m * 16 + g4 * 4 + i;
        if (lrow < Me) {
          size_t hbase = (size_t)(off_e + lrow) * NDIM + by * 256;
#pragma unroll
          for (int n = 0; n < 4; ++n) {
            int col = wc * 64 + n * 16 + r16;
            float v = acc[m][n][i] + bias[e * NDIM + by * 256 + col];
            Hout[hbase + col] = f2bf(fmaxf(v, 0.f));
          }
        }
      }
    }
  } else {
#pragma unroll
    for (int m = 0; m < 8; ++m) {
#pragma unroll
      for (int i = 0; i < 4; ++i) {
        int lrow = bx * 256 + wr * 128 + m * 16 + g4 * 4 + i;
        if (lrow < Me) {
          int tok = lists[e * NTOK + lrow];
          float w = wts[e * NTOK + lrow];
          float* orow = Out + (size_t)tok * NDIM + by * 256;
#pragma unroll
          for (int n = 0; n < 4; ++n) {
            int col = wc * 64 + n * 16 + r16;
            float v = acc[m][n][i] + bias[e * NDIM + by * 256 + col];
            atomicAdd(orow + col, w * v);   // exactly 2 adds/element, commutative
          }
        }
      }
    }
  }
}

extern "C" void kernel_launch(void* const* d_in, const int* in_sizes, int n_in,
                              void* d_out, int out_size, void* d_ws, size_t ws_size,
                              hipStream_t stream) {
  (void)in_sizes; (void)n_in; (void)ws_size;
  const float* x     = (const float*)d_in[0];
  const float* W1    = (const float*)d_in[1];
  const float* b1    = (const float*)d_in[2];
  const float* W2    = (const float*)d_in[3];
  const float* b2    = (const float*)d_in[4];
  const float* Wg    = (const float*)d_in[5];
  const float* bg    = (const float*)d_in[6];
  const float* noise = (const float*)d_in[7];
  float* out = (float*)d_out;

  char* ws = (char*)d_ws;
  int*            counts = (int*)(ws + OFF_CNT);
  int*            lists  = (int*)(ws + OFF_LIST);
  float*          wts    = (float*)(ws + OFF_WTS);
  unsigned short* xbf    = (unsigned short*)(ws + OFF_XBF);
  unsigned short* w1t    = (unsigned short*)(ws + OFF_W1T);
  unsigned short* w2t    = (unsigned short*)(ws + OFF_W2T);
  unsigned short* h      = (unsigned short*)(ws + OFF_H);

  hipFuncSetAttribute(reinterpret_cast<const void*>(moe_gemm_kernel<DDIM, HDIM, true>),
                      hipFuncAttributeMaxDynamicSharedMemorySize, 131072);
  hipFuncSetAttribute(reinterpret_cast<const void*>(moe_gemm_kernel<HDIM, DDIM, false>),
                      hipFuncAttributeMaxDynamicSharedMemorySize, 131072);

  hipMemsetAsync(d_out, 0, (size_t)out_size * sizeof(float), stream);
  hipMemsetAsync(counts, 0, 256, stream);

  gate_kernel<<<NTOK / 4, 256, 0, stream>>>(x, Wg, bg, noise, counts, lists, wts);
  pack_x_kernel<<<(NTOK * DDIM) / 1024, 256, 0, stream>>>(x, xbf);
  transpose_cvt_kernel<<<dim3(HDIM / 64, DDIM / 64, NEXP), 256, 0, stream>>>(W1, w1t, DDIM, HDIM);
  transpose_cvt_kernel<<<dim3(DDIM / 64, HDIM / 64, NEXP), 256, 0, stream>>>(W2, w2t, HDIM, DDIM);

  int g1_nwg = 32 * (HDIM / 256) * NEXP;  // 2048
  int g2_nwg = 32 * (DDIM / 256) * NEXP;  // 1024
  moe_gemm_kernel<DDIM, HDIM, true>
      <<<g1_nwg, 512, 131072, stream>>>(xbf, w1t, b1, counts, lists, wts, h, nullptr);
  moe_gemm_kernel<HDIM, DDIM, false>
      <<<g2_nwg, 512, 131072, stream>>>(h, w2t, b2, counts, lists, wts, nullptr, out);
}